// Round 11
// baseline (120.453 us; speedup 1.0000x reference)
//
#include <hip/hip_runtime.h>
#include <hip/hip_bf16.h>

#define BATCH 4096
#define IN_DIM 3072
#define HID 1024
#define NSTEP 8

typedef __attribute__((ext_vector_type(8))) short short8;
typedef __attribute__((ext_vector_type(4))) float f32x4;
typedef __attribute__((ext_vector_type(4))) unsigned short ushort4v;

__device__ __forceinline__ void gload_lds16(const void* g, void* lds) {
  __builtin_amdgcn_global_load_lds(
      (const __attribute__((address_space(1))) void*)g,
      (__attribute__((address_space(3))) void*)lds, 16, 0, 0);
}

__device__ __forceinline__ unsigned short f32_to_bf16(float f) {
  unsigned int u = __builtin_bit_cast(unsigned int, f);
  unsigned int r = u + 0x7fffu + ((u >> 16) & 1u);
  return (unsigned short)(r >> 16);
}

// BK=32 granule swizzle: physical slot of logical 16B granule g in row r.
// Banks for a 16-row frag read: 8 distinct x 2-way (free, m136).
__device__ __forceinline__ int swz4(int r) { return (r & 3) ^ ((r >> 2) & 3); }

// fused f32 -> bf16 conversion of x, We, Wd (one launch)
__global__ void cvt3_kernel(const float* __restrict__ a,
                            const float* __restrict__ b,
                            const float* __restrict__ c,
                            unsigned short* __restrict__ da,
                            unsigned short* __restrict__ db,
                            unsigned short* __restrict__ dc, int na, int nb,
                            int nc) {
  const int total = na + nb + nc;
  const int stride = gridDim.x * blockDim.x;
  for (int i = blockIdx.x * blockDim.x + threadIdx.x; i < total; i += stride) {
    const float* s;
    unsigned short* d;
    int j = i;
    if (j < na) {
      s = a; d = da;
    } else if (j < na + nb) {
      s = b; d = db; j -= na;
    } else {
      s = c; d = dc; j -= na + nb;
    }
    const float4 v = reinterpret_cast<const float4*>(s)[j];
    ushort4v o;
    o.x = f32_to_bf16(v.x);
    o.y = f32_to_bf16(v.y);
    o.z = f32_to_bf16(v.z);
    o.w = f32_to_bf16(v.w);
    reinterpret_cast<ushort4v*>(d)[j] = o;
  }
}

// Split-K2 reduce (p0+p1+bias) + RK4 nmODE. Writes y f32 (NT) + bf16.
__global__ __launch_bounds__(256) void ode_kernel(
    const float* __restrict__ p0, const float* __restrict__ p1,
    const float* __restrict__ be, float* __restrict__ hid,
    unsigned short* __restrict__ hb, int n4) {
  const float dt = 1.0f / (float)NSTEP;
  const float h2 = 0.5f * dt, hd = dt, h6 = dt / 6.0f;
  int stride = gridDim.x * blockDim.x;
  for (int i = blockIdx.x * blockDim.x + threadIdx.x; i < n4; i += stride) {
    const float4 a4 = reinterpret_cast<const float4*>(p0)[i];
    const float4 b4 = reinterpret_cast<const float4*>(p1)[i];
    const float4 e4 = reinterpret_cast<const float4*>(be)[i & (HID / 4 - 1)];
    float g[4] = {a4.x + b4.x + e4.x, a4.y + b4.y + e4.y,
                  a4.z + b4.z + e4.z, a4.w + b4.w + e4.w};
    float y[4] = {0.0f, 0.0f, 0.0f, 0.0f};
#pragma unroll 1
    for (int s = 0; s < NSTEP; ++s) {
      float k1[4], k2[4], k3[4], k4[4];
#pragma unroll
      for (int e = 0; e < 4; ++e) {
        float t = __sinf(y[e] + g[e]);
        k1[e] = t * t - y[e];
      }
#pragma unroll
      for (int e = 0; e < 4; ++e) {
        float yy = fmaf(h2, k1[e], y[e]);
        float t = __sinf(yy + g[e]);
        k2[e] = t * t - yy;
      }
#pragma unroll
      for (int e = 0; e < 4; ++e) {
        float yy = fmaf(h2, k2[e], y[e]);
        float t = __sinf(yy + g[e]);
        k3[e] = t * t - yy;
      }
#pragma unroll
      for (int e = 0; e < 4; ++e) {
        float yy = fmaf(hd, k3[e], y[e]);
        float t = __sinf(yy + g[e]);
        k4[e] = t * t - yy;
      }
#pragma unroll
      for (int e = 0; e < 4; ++e) {
        float ks = k1[e] + 2.0f * (k2[e] + k3[e]) + k4[e];
        y[e] = fmaf(h6, ks, y[e]);
      }
    }
    f32x4 o4;
    o4[0] = y[0]; o4[1] = y[1]; o4[2] = y[2]; o4[3] = y[3];
    __builtin_nontemporal_store(o4, &reinterpret_cast<f32x4*>(hid)[i]);
    ushort4v ob;
    ob.x = f32_to_bf16(y[0]);
    ob.y = f32_to_bf16(y[1]);
    ob.z = f32_to_bf16(y[2]);
    ob.w = f32_to_bf16(y[3]);
    reinterpret_cast<ushort4v*>(hb)[i] = ob;
  }
}

// m97-style 2-phase NT GEMM: C[M,N] = A[M,K]*B[N,K]^T (+bias).
// 128x128 tile, BK=32, 4 waves (2x2, per-wave 64x64), 32 KB LDS double
// buffer -> ~3 blocks/CU co-resident (the m97 TLP mechanism: other blocks'
// MFMA covers this block's barrier drain). One __syncthreads per K-step;
// compiler-managed waitcnts (validated structure, rounds 2-6).
// Swizzle per rule #21: linear gload_lds dest + inverse-swizzled global
// source + swizzled ds_read, granule map g^swz4(row).
// EPI=0: f32 partial store at Cout + sk*M*N (no bias). EPI=1: bias+sigmoid,
// NT f32 store.
template <int NSK, int EPI>
__global__ __launch_bounds__(256) void gemm2p(
    const unsigned short* __restrict__ A, const unsigned short* __restrict__ B,
    const float* __restrict__ bias, float* __restrict__ Cout, int Kstride,
    int Nout, int nbm, int nbn, int M) {
  constexpr int BM = 128, BN = 128, BK = 32;

  __shared__ unsigned short As[2][BM * BK];
  __shared__ unsigned short Bs[2][BN * BK];

  const int tid = threadIdx.x;
  const int wave = tid >> 6;
  const int lane = tid & 63;
  const int wrow = wave >> 1, wcol = wave & 1;

  // chunked XCD swizzle (grid divisible by 8); bn-fastest, sk-slowest
  const int nwg = gridDim.x;
  const int swz = (blockIdx.x & 7) * (nwg >> 3) + (blockIdx.x >> 3);
  const int tiles = nbm * nbn;
  const int sk = swz / tiles;
  const int rem = swz % tiles;
  const int bn = rem % nbn;
  const int bm = rem / nbn;

  const int Klen = Kstride / NSK;
  const unsigned short* Ablk = A + (size_t)bm * BM * Kstride + sk * Klen;
  const unsigned short* Bblk = B + (size_t)bn * BN * Kstride + sk * Klen;

  const int srow = tid >> 2;       // 0..63: row within a 64-row round
  const int sgr = tid & 3;         // logical granule

  // 4 rounds: r=0,1 -> A rows {0..63},{64..127}; r=2,3 -> B same.
  auto STAGE = [&](int buf, int k0) {
#pragma unroll
    for (int r = 0; r < 4; ++r) {
      const int rr = srow + (r & 1) * 64;
      const int g = sgr ^ swz4(rr);  // inverse-swizzled global source
      if (r < 2)
        gload_lds16(Ablk + (size_t)rr * Kstride + k0 + g * 8,
                    (void*)&As[buf][(r & 1) * 2048 + tid * 8]);
      else
        gload_lds16(Bblk + (size_t)rr * Kstride + k0 + g * 8,
                    (void*)&Bs[buf][(r & 1) * 2048 + tid * 8]);
    }
  };

  const int fr = lane & 15;
  const int hi = lane >> 4;

  f32x4 acc[4][4] = {};

  const int nt = Klen / BK;
  STAGE(0, 0);
#pragma unroll 1
  for (int t = 0; t < nt; ++t) {
    const int buf = t & 1;
    __syncthreads();  // compiler drains vmcnt/lgkm: tile t resident
    if (t + 1 < nt) STAGE(buf ^ 1, (t + 1) * BK);

    short8 af[4], bfr[4];
#pragma unroll
    for (int m = 0; m < 4; ++m) {
      const int row = wrow * 64 + m * 16 + fr;
      const int g = hi ^ swz4(row);  // swizzled read granule
      af[m] = *reinterpret_cast<const short8*>(&As[buf][row * BK + g * 8]);
    }
#pragma unroll
    for (int n = 0; n < 4; ++n) {
      const int row = wcol * 64 + n * 16 + fr;
      const int g = hi ^ swz4(row);
      bfr[n] = *reinterpret_cast<const short8*>(&Bs[buf][row * BK + g * 8]);
    }
#pragma unroll
    for (int m = 0; m < 4; ++m)
#pragma unroll
      for (int n = 0; n < 4; ++n)
        acc[m][n] = __builtin_amdgcn_mfma_f32_16x16x32_bf16(af[m], bfr[n],
                                                            acc[m][n], 0, 0, 0);
  }

  // epilogue: C/D layout col=lane&15, row=(lane>>4)*4+reg (m89-verified)
  const int rowbase = bm * BM + wrow * 64 + hi * 4;
  const int colbase = bn * BN + wcol * 64 + fr;

#pragma unroll
  for (int n = 0; n < 4; ++n) {
    float bv = 0.0f;
    if constexpr (EPI == 1) bv = bias[colbase + n * 16];
#pragma unroll
    for (int m = 0; m < 4; ++m)
#pragma unroll
      for (int r = 0; r < 4; ++r) {
        float v = acc[m][n][r] + bv;
        size_t idx = (size_t)(rowbase + m * 16 + r) * Nout + (colbase + n * 16);
        if constexpr (EPI == 1) {
          v = 1.0f / (1.0f + __expf(-v));
          __builtin_nontemporal_store(v, &Cout[idx]);
        } else {
          Cout[(size_t)sk * M * Nout + idx] = v;
        }
      }
  }
}

extern "C" void kernel_launch(void* const* d_in, const int* in_sizes, int n_in,
                              void* d_out, int out_size, void* d_ws,
                              size_t ws_size, hipStream_t stream) {
  const float* x = (const float*)d_in[0];
  const float* We = (const float*)d_in[1];
  const float* be = (const float*)d_in[2];
  const float* Wd = (const float*)d_in[3];
  const float* bd = (const float*)d_in[4];

  float* out = (float*)d_out;                 // [4096,3072]
  float* hid = out + (size_t)BATCH * IN_DIM;  // [4096,1024]
  // split-K=2 f32 partials (33.6MB) in the out region (50MB); GEMM2 last.
  float* part = out;

  unsigned short* xb = (unsigned short*)d_ws;          // bf16 x   [4096,3072]
  unsigned short* Web = xb + (size_t)BATCH * IN_DIM;   // bf16 We  [1024,3072]
  unsigned short* Wdb = Web + (size_t)HID * IN_DIM;    // bf16 Wd  [3072,1024]
  unsigned short* hb = Wdb + (size_t)IN_DIM * HID;     // bf16 hid [4096,1024]

  cvt3_kernel<<<2048, 256, 0, stream>>>(
      x, We, Wd, xb, Web, Wdb, BATCH * IN_DIM / 4, HID * IN_DIM / 4,
      IN_DIM * HID / 4);

  // GEMM1: f32 partials of x @ We^T. 128x128, BK=32, split-K=2 -> 512 blocks
  // (2/CU, fully resident at ~3/CU capacity)
  gemm2p<2, 0><<<512, 256, 0, stream>>>(xb, Web, nullptr, part, IN_DIM, HID,
                                        BATCH / 128, HID / 128, BATCH);

  // ODE: gamma = p0+p1+be, RK4 -> hid f32 (NT) + hb bf16
  ode_kernel<<<2048, 256, 0, stream>>>(part, part + (size_t)BATCH * HID, be,
                                       hid, hb, BATCH * HID / 4);

  // GEMM2: out = sigmoid(y @ Wd^T + bd). 128x128 -> 32x24 = 768 blocks
  // (exactly 3/CU, uniform, fully resident)
  gemm2p<1, 1><<<768, 256, 0, stream>>>(hb, Wdb, bd, out, HID, IN_DIM,
                                        BATCH / 128, IN_DIM / 128, BATCH);
}